// Round 7
// baseline (254.570 us; speedup 1.0000x reference)
//
#include <hip/hip_runtime.h>

#define NROWS 16384
#define DDIM  4096
#define NEXP  64
#define TAU   1e-3f
#define CB    2048        // combine blocks (8 rows each)
#define RB    2048        // repair worker blocks
#define RBLK  64          // reduce_stage blocks

// ---------------- Kernel A: fp32 partial GEMM ----------------
// 256 threads (4 waves), BM=256 rows x 64 experts, DK=16, per-thread 8x8.
// LDS DOUBLE-BUFFERED (40 KB): ONE barrier per K-tile. Prefetch loads are
// issued BEFORE the barrier (land during compute); LDS writes of the
// prefetched tile happen AFTER compute into buf^1 (idle since the barrier).
__global__ __launch_bounds__(256) void gemm_partial(
    const float* __restrict__ x, const float* __restrict__ Wg,
    float* __restrict__ partials, int* __restrict__ counter, int ks_shift)
{
    if (blockIdx.x == 0 && threadIdx.x == 0) *counter = 0;

    __shared__ float xT[2][16 * 256];  // 32 KB [buf][k][row]
    __shared__ float Wt[2][16 * 64];   //  8 KB [buf][k][e]

    const int tid = threadIdx.x;
    const int rg  = tid >> 3;       // 0..31: rows rg*8..+7
    const int cg  = tid & 7;        // 0..7 : cols cg*8..+7
    const int KS   = 1 << ks_shift;
    const int kper = DDIM >> ks_shift;
    const int T    = kper >> 4;
    const int rb   = (int)blockIdx.x >> ks_shift;
    const int kq   = (int)blockIdx.x & (KS - 1);

    const float* xbase = x + (size_t)(rb * 256 + tid) * DDIM + kq * kper;
    const float* wbase = Wg + (size_t)(kq * kper) * NEXP;

    float4 px[4], pw;
    #pragma unroll
    for (int q = 0; q < 4; ++q) px[q] = *(const float4*)(xbase + q * 4);
    pw = *(const float4*)(wbase + (size_t)tid * 4);
    #pragma unroll
    for (int q = 0; q < 4; ++q) {                // write tile 0 -> buf 0
        xT[0][(q * 4 + 0) * 256 + tid] = px[q].x;
        xT[0][(q * 4 + 1) * 256 + tid] = px[q].y;
        xT[0][(q * 4 + 2) * 256 + tid] = px[q].z;
        xT[0][(q * 4 + 3) * 256 + tid] = px[q].w;
    }
    *(float4*)&Wt[0][tid * 4] = pw;

    float acc[8][8];
    #pragma unroll
    for (int i = 0; i < 8; ++i)
        #pragma unroll
        for (int j = 0; j < 8; ++j) acc[i][j] = 0.f;

    int cur = 0;
    for (int t = 0; t < T; ++t) {
        if (t + 1 < T) {                         // ISSUE loads for t+1 (early)
            const float* xp = xbase + (t + 1) * 16;
            const float* wp = wbase + (size_t)(t + 1) * 16 * NEXP;
            #pragma unroll
            for (int q = 0; q < 4; ++q) px[q] = *(const float4*)(xp + q * 4);
            pw = *(const float4*)(wp + (size_t)tid * 4);
        }
        __syncthreads();                         // buf[cur] ready
        const float* xc = &xT[cur][0];
        const float* wc = &Wt[cur][0];
        #pragma unroll
        for (int k = 0; k < 16; ++k) {
            const float4 a0 = *(const float4*)&xc[k * 256 + rg * 8];
            const float4 a1 = *(const float4*)&xc[k * 256 + rg * 8 + 4];
            const float4 b0 = *(const float4*)&wc[k * 64 + cg * 8];
            const float4 b1 = *(const float4*)&wc[k * 64 + cg * 8 + 4];
            const float a[8] = {a0.x, a0.y, a0.z, a0.w, a1.x, a1.y, a1.z, a1.w};
            const float b[8] = {b0.x, b0.y, b0.z, b0.w, b1.x, b1.y, b1.z, b1.w};
            #pragma unroll
            for (int i = 0; i < 8; ++i)
                #pragma unroll
                for (int j = 0; j < 8; ++j)
                    acc[i][j] = fmaf(a[i], b[j], acc[i][j]);
        }
        if (t + 1 < T) {                         // WRITE prefetched -> buf^1 (late)
            float* xn = &xT[cur ^ 1][0];
            #pragma unroll
            for (int q = 0; q < 4; ++q) {
                xn[(q * 4 + 0) * 256 + tid] = px[q].x;
                xn[(q * 4 + 1) * 256 + tid] = px[q].y;
                xn[(q * 4 + 2) * 256 + tid] = px[q].z;
                xn[(q * 4 + 3) * 256 + tid] = px[q].w;
            }
            *(float4*)&Wt[cur ^ 1][tid * 4] = pw;
        }
        cur ^= 1;
    }

    float* po = partials + ((size_t)(rb << ks_shift) + kq) * (256 * 64);
    #pragma unroll
    for (int i = 0; i < 8; ++i) {
        *(float4*)(po + (rg * 8 + i) * 64 + cg * 8) =
            make_float4(acc[i][0], acc[i][1], acc[i][2], acc[i][3]);
        *(float4*)(po + (rg * 8 + i) * 64 + cg * 8 + 4) =
            make_float4(acc[i][4], acc[i][5], acc[i][6], acc[i][7]);
    }
}

// ---------------- Kernel B: combine + softmax + top-9 + worklist ----------------
__global__ __launch_bounds__(256) void combine_epilogue(
    const float* __restrict__ partials, const float* __restrict__ noise,
    float* __restrict__ out_gates, float* __restrict__ out_idx,
    float* __restrict__ ws_imp, float* __restrict__ ws_load,
    int* __restrict__ worklist, int* __restrict__ counter, int ks_shift)
{
    __shared__ float red[4][NEXP];
    const int tid = threadIdx.x, lane = tid & 63, w = tid >> 6;
    const int KS = 1 << ks_shift;

    float impacc = 0.f, loadacc = 0.f;
    #pragma unroll
    for (int rr = 0; rr < 2; ++rr) {
        const int grow = (int)blockIdx.x * 8 + w * 2 + rr;
        const int rb = grow >> 8, row = grow & 255;     // BM=256 partial tiles
        float v = noise[(size_t)grow * NEXP + lane];
        const float* pp = partials + ((size_t)(rb << ks_shift)) * (256 * 64)
                          + row * 64 + lane;
        for (int q = 0; q < KS; ++q) v += pp[(size_t)q * (256 * 64)]; // fixed order

        float m = v;
        #pragma unroll
        for (int off = 32; off; off >>= 1) m = fmaxf(m, __shfl_xor(m, off));
        const float ex = __expf(v - m);
        float s = ex;
        #pragma unroll
        for (int off = 32; off; off >>= 1) s += __shfl_xor(s, off);
        const float g = ex * (1.0f / s);
        impacc += g;

        float work = v, vprev = 0.f;
        float myv = 0.f, sumtop = 0.f;
        int myi = 0, mine = 0, flg = 0;
        #pragma unroll
        for (int j = 0; j < 9; ++j) {
            float bv = work, bg = g; int bi = lane;
            #pragma unroll
            for (int off = 32; off; off >>= 1) {
                const float ov = __shfl_xor(bv, off);
                const int   oi = __shfl_xor(bi, off);
                const float og = __shfl_xor(bg, off);
                if (ov > bv || (ov == bv && oi < bi)) { bv = ov; bi = oi; bg = og; }
            }
            if (j > 0) flg |= (vprev - bv < TAU) ? 1 : 0;
            vprev = bv;
            if (j < 8) {
                sumtop += bg;
                if (lane == j)  { myv = bg; myi = bi; }
                if (lane == bi) { work = -3e38f; mine = 1; }
            }
        }
        loadacc += (float)mine;

        if (lane < 8) {
            out_gates[(size_t)grow * 8 + lane] = myv / sumtop;
            out_idx  [(size_t)grow * 8 + lane] = (float)myi;
        }
        if (lane == 0 && flg) {
            const int pos = atomicAdd(counter, 1);
            worklist[pos] = grow;
        }
    }

    red[w][lane] = impacc;
    __syncthreads();
    if (w == 0)
        ws_imp[(size_t)blockIdx.x * NEXP + lane] =
            red[0][lane] + red[1][lane] + red[2][lane] + red[3][lane];
    __syncthreads();
    red[w][lane] = loadacc;
    __syncthreads();
    if (w == 0)
        ws_load[(size_t)blockIdx.x * NEXP + lane] =
            red[0][lane] + red[1][lane] + red[2][lane] + red[3][lane];
}

// ---------------- Kernel B2: stage-1 loss reduction (2048 -> 64) ----------------
__global__ __launch_bounds__(256) void reduce_stage(
    const float* __restrict__ ws_imp, const float* __restrict__ ws_load,
    float* __restrict__ st_imp, float* __restrict__ st_load)
{
    __shared__ float si[4][NEXP], sl[4][NEXP];
    const int tid = threadIdx.x, e = tid & 63, sub = tid >> 6;
    float a = 0.f, b = 0.f;
    #pragma unroll
    for (int i = 0; i < 8; ++i) {
        const int blk = (int)blockIdx.x * 32 + sub * 8 + i;
        a += ws_imp[(size_t)blk * NEXP + e];
        b += ws_load[(size_t)blk * NEXP + e];
    }
    si[sub][e] = a; sl[sub][e] = b;
    __syncthreads();
    if (sub == 0) {
        st_imp [(size_t)blockIdx.x * NEXP + e] = si[0][e] + si[1][e] + si[2][e] + si[3][e];
        st_load[(size_t)blockIdx.x * NEXP + e] = sl[0][e] + sl[1][e] + sl[2][e] + sl[3][e];
    }
}

// ---------------- Kernel C: fp64 repair (worklist) + loss finalize ----------------
__global__ __launch_bounds__(256) void repair_finalize(
    const float* __restrict__ x, const float* __restrict__ Wg,
    const float* __restrict__ noise, const int* __restrict__ worklist,
    const int* __restrict__ counter, const float* __restrict__ st_imp,
    const float* __restrict__ st_load, float* __restrict__ out_gates,
    float* __restrict__ out_idx, float* __restrict__ loss_out)
{
    const int tid = threadIdx.x, lane = tid & 63, w = tid >> 6;

    if (blockIdx.x == RB) {                     // ---- loss finalize ----
        __shared__ float si[4][NEXP], sl[4][NEXP];
        float a = 0.f, b = 0.f;
        #pragma unroll
        for (int j = 0; j < RBLK / 4; ++j) {
            const int blk = w * (RBLK / 4) + j;
            a += st_imp[(size_t)blk * NEXP + lane];
            b += st_load[(size_t)blk * NEXP + lane];
        }
        si[w][lane] = a; sl[w][lane] = b;
        __syncthreads();
        if (w == 0) {
            const float imp = (si[0][lane] + si[1][lane] + si[2][lane] + si[3][lane])
                              / (float)NROWS;
            const float ld  = (sl[0][lane] + sl[1][lane] + sl[2][lane] + sl[3][lane])
                              / (float)(NROWS * 8);
            float term = imp * ld;
            #pragma unroll
            for (int off = 32; off; off >>= 1) term += __shfl_xor(term, off);
            if (lane == 0) *loss_out = term * (float)NEXP;
        }
        return;
    }

    // ---- repair: ~1 flagged row per block; 8 fp64 chains, 32 loads in flight
    __shared__ float xr[DDIM];          // 16 KB
    __shared__ double red64[4][NEXP];   // 2 KB
    const int count = *counter;

    for (int i = (int)blockIdx.x; i < count; i += RB) {
        const int grow = worklist[i];
        __syncthreads();                // prior iteration's LDS consumed
        #pragma unroll
        for (int q = 0; q < 4; ++q)
            ((float4*)xr)[tid + 256 * q] =
                ((const float4*)(x + (size_t)grow * DDIM))[tid + 256 * q];
        __syncthreads();

        // wave w covers k-chunk w*1024; lane = expert
        double ch[8];
        #pragma unroll
        for (int c = 0; c < 8; ++c) ch[c] = 0.0;
        const float* wp = Wg + (size_t)(w * 1024) * NEXP + lane;
        const float* xp = xr + w * 1024;
        #pragma unroll 4
        for (int k = 0; k < 1024; k += 8) {
            #pragma unroll
            for (int c = 0; c < 8; ++c)
                ch[c] = fma((double)xp[k + c],
                            (double)wp[(size_t)(k + c) * NEXP], ch[c]);
        }
        red64[w][lane] = (((ch[0] + ch[1]) + (ch[2] + ch[3]))
                        + ((ch[4] + ch[5]) + (ch[6] + ch[7])));
        __syncthreads();

        if (w == 0) {
            const double v64 = (((red64[0][lane] + red64[1][lane]) + red64[2][lane])
                                + red64[3][lane]) + (double)noise[(size_t)grow * NEXP + lane];
            double m = v64;
            #pragma unroll
            for (int off = 32; off; off >>= 1) m = fmax(m, __shfl_xor(m, off));
            const float ex = __expf((float)(v64 - m));
            float s = ex;
            #pragma unroll
            for (int off = 32; off; off >>= 1) s += __shfl_xor(s, off);
            const float g = ex * (1.0f / s);

            double work = v64;
            float myv = 0.f, sumtop = 0.f, bg;
            int myi = 0;
            #pragma unroll
            for (int j = 0; j < 8; ++j) {
                double bv = work; int bi = lane; bg = g;
                #pragma unroll
                for (int off = 32; off; off >>= 1) {
                    const double ov = __shfl_xor(bv, off);
                    const int    oi = __shfl_xor(bi, off);
                    const float  og = __shfl_xor(bg, off);
                    if (ov > bv || (ov == bv && oi < bi)) { bv = ov; bi = oi; bg = og; }
                }
                sumtop += bg;
                if (lane == j)  { myv = bg; myi = bi; }
                if (lane == bi) work = -1e300;
            }
            if (lane < 8) {
                out_gates[(size_t)grow * 8 + lane] = myv / sumtop;
                out_idx  [(size_t)grow * 8 + lane] = (float)myi;
            }
        }
    }
}

extern "C" void kernel_launch(void* const* d_in, const int* in_sizes, int n_in,
                              void* d_out, int out_size, void* d_ws, size_t ws_size,
                              hipStream_t stream) {
    const float* x     = (const float*)d_in[0];
    const float* Wg    = (const float*)d_in[1];
    const float* noise = (const float*)d_in[2];
    float* out       = (float*)d_out;
    float* out_gates = out;
    float* out_idx   = out + (size_t)NROWS * 8;
    float* loss_out  = out + (size_t)2 * NROWS * 8;

    const size_t misc = ((size_t)2 * CB * NEXP + 2 * RBLK * NEXP + NROWS + 64) * 4;
    int ks_shift = 4;
    while (ks_shift > 0 &&
           ((size_t)64 * (1u << ks_shift) * (256 * 64) * 4 + misc) > ws_size)
        --ks_shift;
    const int KS = 1 << ks_shift;

    float* partials = (float*)d_ws;
    float* ws_imp   = partials + (size_t)64 * KS * (256 * 64);
    float* ws_load  = ws_imp + (size_t)CB * NEXP;
    float* st_imp   = ws_load + (size_t)CB * NEXP;
    float* st_load  = st_imp + (size_t)RBLK * NEXP;
    int*   worklist = (int*)(st_load + (size_t)RBLK * NEXP);
    int*   counter  = worklist + NROWS;

    gemm_partial    <<<64 * KS, 256, 0, stream>>>(x, Wg, partials, counter, ks_shift);
    combine_epilogue<<<CB,      256, 0, stream>>>(partials, noise, out_gates, out_idx,
                                                  ws_imp, ws_load, worklist, counter,
                                                  ks_shift);
    reduce_stage    <<<RBLK,    256, 0, stream>>>(ws_imp, ws_load, st_imp, st_load);
    repair_finalize <<<RB + 1,  256, 0, stream>>>(x, Wg, noise, worklist, counter,
                                                  st_imp, st_load, out_gates, out_idx,
                                                  loss_out);
}

// Round 8
// 181.556 us; speedup vs baseline: 1.4022x; 1.4022x over previous
//
#include <hip/hip_runtime.h>

#define NROWS 16384
#define DDIM  4096
#define NEXP  64
#define TAU   1e-3f
#define FB    512         // fused blocks, 32 rows each
#define RB    2048        // repair worker blocks
#define RBLK  64          // reduce_stage output blocks

typedef __attribute__((ext_vector_type(8))) short bf16x8;
typedef __attribute__((ext_vector_type(4))) float f32x4;

__device__ __forceinline__ ushort f2bf(float f) {   // fp32 -> bf16 RN-even
    uint u = __float_as_uint(f);
    u += 0x7FFFu + ((u >> 16) & 1u);
    return (ushort)(u >> 16);
}
__device__ __forceinline__ float bf2f(ushort h) {
    return __uint_as_float(((uint)h) << 16);
}

// ---------------- Kernel A: fused split-bf16 MFMA GEMM + epilogue ----------------
// 512 blocks x 256 thr; block rb owns rows rb*32..+31, ALL 64 experts, full K.
// Per 64-k chunk: stage x(32x64) and W(64x64) as bf16 hi/lo into LDS (XOR
// swizzle k^=(row&7)*8 for conflict-free b128), 3-product MFMA accumulate.
// logits = x_hi*W_hi + x_hi*W_lo + x_lo*W_hi in fp32 accs (err ~1e-5, within
// the validated tau=1e-3 + fp64-repair margin). Epilogue fused (no partials).
__global__ __launch_bounds__(256) void router_fused(
    const float* __restrict__ x, const float* __restrict__ Wg,
    const float* __restrict__ noise, float* __restrict__ out_gates,
    float* __restrict__ out_idx, float* __restrict__ ws_imp,
    float* __restrict__ ws_load, int* __restrict__ worklist,
    int* __restrict__ counter)
{
    __shared__ ushort xhi[2][32 * 64], xlo[2][32 * 64];   // 4 KB each
    __shared__ ushort whi[2][64 * 64], wlo[2][64 * 64];   // 8 KB each
    __shared__ float logits_s[32 * 65];                   // 8.3 KB
    __shared__ float red[4][NEXP];

    const int tid  = threadIdx.x;
    const int lane = tid & 63;
    const int w    = tid >> 6;
    const int rb   = blockIdx.x;

    // staging maps
    const int sxr = tid >> 3;           // x row 0..31
    const int sxk = (tid & 7) * 8;      // x k0 (8 floats)
    const int swe = tid & 63;           // W expert (lane-coalesced dword reads)
    const int swk = (tid >> 6) * 16;    // W k0 (16 k-values)
    const int psx = sxk ^ ((sxr & 7) * 8);
    const int sww = (swe & 7) * 8;

    const float* xsrc = x + (size_t)(rb * 32 + sxr) * DDIM + sxk;
    const float* wsrc = Wg + (size_t)swk * NEXP + swe;

    // compute maps (mfma 16x16x32)
    const int rt = w & 1, ch = w >> 1;
    const int fr = lane & 15;
    const int fk = (lane >> 4) * 8;
    const int arow = rt * 16 + fr;
    const int sa   = (arow & 7) * 8;
    const int e0   = ch * 32 + fr;      // n=0 tile col; n=1 is e0+16 (same &7)
    const int sb   = (e0 & 7) * 8;

    // ---- prologue: chunk 0 ----
    float4 px0 = *(const float4*)(xsrc);
    float4 px1 = *(const float4*)(xsrc + 4);
    float pwf[16];
    #pragma unroll
    for (int i = 0; i < 16; ++i) pwf[i] = wsrc[(size_t)i * NEXP];

    #define STAGE(BUF)                                                        \
    do {                                                                      \
        const float vv[8] = {px0.x, px0.y, px0.z, px0.w,                      \
                             px1.x, px1.y, px1.z, px1.w};                     \
        bf16x8 H, L;                                                          \
        _Pragma("unroll")                                                     \
        for (int i = 0; i < 8; ++i) {                                         \
            const ushort h = f2bf(vv[i]);                                     \
            H[i] = (short)h; L[i] = (short)f2bf(vv[i] - bf2f(h));             \
        }                                                                     \
        *(bf16x8*)&xhi[BUF][sxr * 64 + psx] = H;                              \
        *(bf16x8*)&xlo[BUF][sxr * 64 + psx] = L;                              \
        bf16x8 WH0, WH1, WL0, WL1;                                            \
        _Pragma("unroll")                                                     \
        for (int i = 0; i < 8; ++i) {                                         \
            const ushort h0 = f2bf(pwf[i]);                                   \
            WH0[i] = (short)h0; WL0[i] = (short)f2bf(pwf[i] - bf2f(h0));      \
            const ushort h1 = f2bf(pwf[8 + i]);                               \
            WH1[i] = (short)h1; WL1[i] = (short)f2bf(pwf[8 + i] - bf2f(h1));  \
        }                                                                     \
        *(bf16x8*)&whi[BUF][swe * 64 + (swk ^ sww)]       = WH0;              \
        *(bf16x8*)&whi[BUF][swe * 64 + ((swk + 8) ^ sww)] = WH1;              \
        *(bf16x8*)&wlo[BUF][swe * 64 + (swk ^ sww)]       = WL0;              \
        *(bf16x8*)&wlo[BUF][swe * 64 + ((swk + 8) ^ sww)] = WL1;              \
    } while (0)

    STAGE(0);

    f32x4 acc0 = {0.f, 0.f, 0.f, 0.f};
    f32x4 acc1 = {0.f, 0.f, 0.f, 0.f};

    const int T = DDIM / 64;            // 64 chunks
    int cur = 0;
    for (int t = 0; t < T; ++t) {
        if (t + 1 < T) {                // T14: issue next-chunk loads EARLY
            px0 = *(const float4*)(xsrc + (t + 1) * 64);
            px1 = *(const float4*)(xsrc + (t + 1) * 64 + 4);
            #pragma unroll
            for (int i = 0; i < 16; ++i)
                pwf[i] = wsrc[(size_t)((t + 1) * 64 + i) * NEXP];
        }
        __syncthreads();                // buf[cur] fully staged by all waves
        const ushort* xh = xhi[cur]; const ushort* xl = xlo[cur];
        const ushort* wh = whi[cur]; const ushort* wl = wlo[cur];
        #pragma unroll
        for (int ks = 0; ks < 2; ++ks) {
            const int kb = ks * 32 + fk;
            const bf16x8 ah  = *(const bf16x8*)&xh[arow * 64 + (kb ^ sa)];
            const bf16x8 al  = *(const bf16x8*)&xl[arow * 64 + (kb ^ sa)];
            const bf16x8 bh0 = *(const bf16x8*)&wh[e0 * 64 + (kb ^ sb)];
            const bf16x8 bl0 = *(const bf16x8*)&wl[e0 * 64 + (kb ^ sb)];
            const bf16x8 bh1 = *(const bf16x8*)&wh[(e0 + 16) * 64 + (kb ^ sb)];
            const bf16x8 bl1 = *(const bf16x8*)&wl[(e0 + 16) * 64 + (kb ^ sb)];
            acc0 = __builtin_amdgcn_mfma_f32_16x16x32_bf16(ah, bh0, acc0, 0, 0, 0);
            acc0 = __builtin_amdgcn_mfma_f32_16x16x32_bf16(ah, bl0, acc0, 0, 0, 0);
            acc0 = __builtin_amdgcn_mfma_f32_16x16x32_bf16(al, bh0, acc0, 0, 0, 0);
            acc1 = __builtin_amdgcn_mfma_f32_16x16x32_bf16(ah, bh1, acc1, 0, 0, 0);
            acc1 = __builtin_amdgcn_mfma_f32_16x16x32_bf16(ah, bl1, acc1, 0, 0, 0);
            acc1 = __builtin_amdgcn_mfma_f32_16x16x32_bf16(al, bh1, acc1, 0, 0, 0);
        }
        if (t + 1 < T) STAGE(cur ^ 1);  // T14: write LATE into idle buffer
        cur ^= 1;
    }
    #undef STAGE

    // ---- epilogue: acc -> logits LDS (verified C/D layout) ----
    const int orow = rt * 16 + (lane >> 4) * 4;
    #pragma unroll
    for (int r = 0; r < 4; ++r) {
        logits_s[(orow + r) * 65 + ch * 32 + fr]      = acc0[r];
        logits_s[(orow + r) * 65 + ch * 32 + 16 + fr] = acc1[r];
    }
    __syncthreads();

    float impacc = 0.f, loadacc = 0.f;
    #pragma unroll
    for (int rr = 0; rr < 8; ++rr) {
        const int row  = w * 8 + rr;
        const int grow = rb * 32 + row;
        float v = logits_s[row * 65 + lane] + noise[(size_t)grow * NEXP + lane];

        float m = v;
        #pragma unroll
        for (int off = 32; off; off >>= 1) m = fmaxf(m, __shfl_xor(m, off));
        const float ex = __expf(v - m);
        float s = ex;
        #pragma unroll
        for (int off = 32; off; off >>= 1) s += __shfl_xor(s, off);
        const float g = ex * (1.0f / s);
        impacc += g;

        float work = v, vprev = 0.f;
        float myv = 0.f, sumtop = 0.f;
        int myi = 0, mine = 0, flg = 0;
        #pragma unroll
        for (int j = 0; j < 9; ++j) {
            float bv = work, bg = g; int bi = lane;
            #pragma unroll
            for (int off = 32; off; off >>= 1) {
                const float ov = __shfl_xor(bv, off);
                const int   oi = __shfl_xor(bi, off);
                const float og = __shfl_xor(bg, off);
                if (ov > bv || (ov == bv && oi < bi)) { bv = ov; bi = oi; bg = og; }
            }
            if (j > 0) flg |= (vprev - bv < TAU) ? 1 : 0;
            vprev = bv;
            if (j < 8) {
                sumtop += bg;
                if (lane == j)  { myv = bg; myi = bi; }
                if (lane == bi) { work = -3e38f; mine = 1; }
            }
        }
        loadacc += (float)mine;

        if (lane < 8) {
            out_gates[(size_t)grow * 8 + lane] = myv / sumtop;
            out_idx  [(size_t)grow * 8 + lane] = (float)myi;
        }
        if (lane == 0 && flg) {
            const int pos = atomicAdd(counter, 1);
            worklist[pos] = grow;
        }
    }

    red[w][lane] = impacc;
    __syncthreads();
    if (w == 0)
        ws_imp[(size_t)rb * NEXP + lane] =
            red[0][lane] + red[1][lane] + red[2][lane] + red[3][lane];
    __syncthreads();
    red[w][lane] = loadacc;
    __syncthreads();
    if (w == 0)
        ws_load[(size_t)rb * NEXP + lane] =
            red[0][lane] + red[1][lane] + red[2][lane] + red[3][lane];
}

// ---------------- Kernel B: stage-1 loss reduction (512 -> 64) ----------------
__global__ __launch_bounds__(256) void reduce_stage(
    const float* __restrict__ ws_imp, const float* __restrict__ ws_load,
    float* __restrict__ st_imp, float* __restrict__ st_load)
{
    __shared__ float si[4][NEXP], sl[4][NEXP];
    const int tid = threadIdx.x, e = tid & 63, sub = tid >> 6;
    float a = 0.f, b = 0.f;
    #pragma unroll
    for (int i = 0; i < 2; ++i) {
        const int blk = (int)blockIdx.x * 8 + sub * 2 + i;
        a += ws_imp[(size_t)blk * NEXP + e];
        b += ws_load[(size_t)blk * NEXP + e];
    }
    si[sub][e] = a; sl[sub][e] = b;
    __syncthreads();
    if (sub == 0) {
        st_imp [(size_t)blockIdx.x * NEXP + e] = si[0][e] + si[1][e] + si[2][e] + si[3][e];
        st_load[(size_t)blockIdx.x * NEXP + e] = sl[0][e] + sl[1][e] + sl[2][e] + sl[3][e];
    }
}

// ---------------- Kernel C: fp64 repair (worklist) + loss finalize ----------------
__global__ __launch_bounds__(256) void repair_finalize(
    const float* __restrict__ x, const float* __restrict__ Wg,
    const float* __restrict__ noise, const int* __restrict__ worklist,
    const int* __restrict__ counter, const float* __restrict__ st_imp,
    const float* __restrict__ st_load, float* __restrict__ out_gates,
    float* __restrict__ out_idx, float* __restrict__ loss_out)
{
    const int tid = threadIdx.x, lane = tid & 63, w = tid >> 6;

    if (blockIdx.x == RB) {                     // ---- loss finalize ----
        __shared__ float si[4][NEXP], sl[4][NEXP];
        float a = 0.f, b = 0.f;
        #pragma unroll
        for (int j = 0; j < RBLK / 4; ++j) {
            const int blk = w * (RBLK / 4) + j;
            a += st_imp[(size_t)blk * NEXP + lane];
            b += st_load[(size_t)blk * NEXP + lane];
        }
        si[w][lane] = a; sl[w][lane] = b;
        __syncthreads();
        if (w == 0) {
            const float imp = (si[0][lane] + si[1][lane] + si[2][lane] + si[3][lane])
                              / (float)NROWS;
            const float ld  = (sl[0][lane] + sl[1][lane] + sl[2][lane] + sl[3][lane])
                              / (float)(NROWS * 8);
            float term = imp * ld;
            #pragma unroll
            for (int off = 32; off; off >>= 1) term += __shfl_xor(term, off);
            if (lane == 0) *loss_out = term * (float)NEXP;
        }
        return;
    }

    // ---- repair: ~1 flagged row per block; 8 fp64 chains ----
    __shared__ float xr[DDIM];
    __shared__ double red64[4][NEXP];
    const int count = *counter;

    for (int i = (int)blockIdx.x; i < count; i += RB) {
        const int grow = worklist[i];
        __syncthreads();
        #pragma unroll
        for (int q = 0; q < 4; ++q)
            ((float4*)xr)[tid + 256 * q] =
                ((const float4*)(x + (size_t)grow * DDIM))[tid + 256 * q];
        __syncthreads();

        double ch[8];
        #pragma unroll
        for (int c = 0; c < 8; ++c) ch[c] = 0.0;
        const float* wp = Wg + (size_t)(w * 1024) * NEXP + lane;
        const float* xp = xr + w * 1024;
        #pragma unroll 4
        for (int k = 0; k < 1024; k += 8) {
            #pragma unroll
            for (int c = 0; c < 8; ++c)
                ch[c] = fma((double)xp[k + c],
                            (double)wp[(size_t)(k + c) * NEXP], ch[c]);
        }
        red64[w][lane] = (((ch[0] + ch[1]) + (ch[2] + ch[3]))
                        + ((ch[4] + ch[5]) + (ch[6] + ch[7])));
        __syncthreads();

        if (w == 0) {
            const double v64 = (((red64[0][lane] + red64[1][lane]) + red64[2][lane])
                                + red64[3][lane]) + (double)noise[(size_t)grow * NEXP + lane];
            double m = v64;
            #pragma unroll
            for (int off = 32; off; off >>= 1) m = fmax(m, __shfl_xor(m, off));
            const float ex = __expf((float)(v64 - m));
            float s = ex;
            #pragma unroll
            for (int off = 32; off; off >>= 1) s += __shfl_xor(s, off);
            const float g = ex * (1.0f / s);

            double work = v64;
            float myv = 0.f, sumtop = 0.f, bg;
            int myi = 0;
            #pragma unroll
            for (int j = 0; j < 8; ++j) {
                double bv = work; int bi = lane; bg = g;
                #pragma unroll
                for (int off = 32; off; off >>= 1) {
                    const double ov = __shfl_xor(bv, off);
                    const int    oi = __shfl_xor(bi, off);
                    const float  og = __shfl_xor(bg, off);
                    if (ov > bv || (ov == bv && oi < bi)) { bv = ov; bi = oi; bg = og; }
                }
                sumtop += bg;
                if (lane == j)  { myv = bg; myi = bi; }
                if (lane == bi) work = -1e300;
            }
            if (lane < 8) {
                out_gates[(size_t)grow * 8 + lane] = myv / sumtop;
                out_idx  [(size_t)grow * 8 + lane] = (float)myi;
            }
        }
    }
}

extern "C" void kernel_launch(void* const* d_in, const int* in_sizes, int n_in,
                              void* d_out, int out_size, void* d_ws, size_t ws_size,
                              hipStream_t stream) {
    const float* x     = (const float*)d_in[0];
    const float* Wg    = (const float*)d_in[1];
    const float* noise = (const float*)d_in[2];
    float* out       = (float*)d_out;
    float* out_gates = out;
    float* out_idx   = out + (size_t)NROWS * 8;
    float* loss_out  = out + (size_t)2 * NROWS * 8;

    float* ws_imp   = (float*)d_ws;                        // FB*64
    float* ws_load  = ws_imp + (size_t)FB * NEXP;          // FB*64
    float* st_imp   = ws_load + (size_t)FB * NEXP;         // 64*64
    float* st_load  = st_imp + (size_t)RBLK * NEXP;        // 64*64
    int*   worklist = (int*)(st_load + (size_t)RBLK * NEXP);
    int*   counter  = worklist + NROWS;

    hipMemsetAsync(counter, 0, sizeof(int), stream);
    router_fused   <<<FB,     256, 0, stream>>>(x, Wg, noise, out_gates, out_idx,
                                                ws_imp, ws_load, worklist, counter);
    reduce_stage   <<<RBLK,   256, 0, stream>>>(ws_imp, ws_load, st_imp, st_load);
    repair_finalize<<<RB + 1, 256, 0, stream>>>(x, Wg, noise, worklist, counter,
                                                st_imp, st_load, out_gates, out_idx,
                                                loss_out);
}